// Round 1
// baseline (783.642 us; speedup 1.0000x reference)
//
#include <hip/hip_runtime.h>

#define B_  16
#define T_  2048
#define R_  256
#define NS_ 4

typedef unsigned short u16;
typedef __attribute__((ext_vector_type(8))) __bf16 bf16x8;
typedef __attribute__((ext_vector_type(4))) float f32x4;

__device__ __forceinline__ u16 f2bf(float f){
  union { float f; unsigned u; } x; x.f = f;
  unsigned r = x.u + 0x7FFFu + ((x.u >> 16) & 1u);
  return (u16)(r >> 16);
}
__device__ __forceinline__ float bf2f(u16 h){
  union { unsigned u; float f; } x; x.u = ((unsigned)h) << 16; return x.f;
}

// async global->LDS, 16B per lane. LDS dest must be wave-uniform base; HW
// writes lane i at base + i*16 (guide §5). Our chunk order matches that.
__device__ __forceinline__ void async_cp16(const void* g, void* l){
  __builtin_amdgcn_global_load_lds((__attribute__((address_space(1))) void*)g,
                                   (__attribute__((address_space(3))) void*)l,
                                   16, 0, 0);
}

// ---------------------------------------------------------------- convert
__global__ __launch_bounds__(256)
void cvt_kernel(const float* __restrict__ src, u16* __restrict__ dst, int n4){
  int i = blockIdx.x*256 + threadIdx.x;
  if (i >= n4) return;
  float4 f = ((const float4*)src)[i];
  ushort4 o;
  o.x = f2bf(f.x); o.y = f2bf(f.y); o.z = f2bf(f.z); o.w = f2bf(f.w);
  ((ushort4*)dst)[i] = o;
}

// ------------------------------------------------- generic NT GEMM (bf16)
// C[m][n] = sum_k A[m][k]*B[n][k] + bias ; C stored bf16.
// z decode: n = z&3 (weight/bias select), b = z>>2 (batch select).
// biasMode 0: bias indexed by col (N). biasMode 1: bias indexed by row (M).
__global__ __launch_bounds__(256, 2)
void gemm_nt_bias(const u16* __restrict__ A, const u16* __restrict__ Bm,
                  u16* __restrict__ C, const float* __restrict__ bias,
                  int lda, int ldb, int ldc, int K,
                  long long sAn, long long sBb, long long sCz,
                  int sBiasN, int biasMode)
{
  __shared__ __align__(16) u16 As[128*32];
  __shared__ __align__(16) u16 Bs[128*32];
  int tid = threadIdx.x;
  int lane = tid & 63, wave = tid >> 6;
  int z = blockIdx.z;
  int nIdx = z & 3, bIdx = z >> 2;
  A    += (long long)nIdx * sAn;
  Bm   += (long long)bIdx * sBb;
  C    += (long long)z * sCz;
  bias += (long long)nIdx * sBiasN;
  int mBase = blockIdx.y * 128;
  int nBase = blockIdx.x * 128;
  int wm = (wave >> 1) * 64, wn = (wave & 1) * 64;
  int quad = lane >> 4, lc = lane & 15;

  f32x4 acc[4][4];
  #pragma unroll
  for (int i=0;i<4;i++)
    #pragma unroll
    for (int j=0;j<4;j++) acc[i][j] = (f32x4){0.f,0.f,0.f,0.f};

  for (int k0=0; k0<K; k0+=32){
    #pragma unroll
    for (int r=0;r<2;r++){
      int c = r*256 + tid;
      int row = c >> 2, col = (c & 3)*8;
      async_cp16(A  + (long long)(mBase+row)*lda + k0 + col, (void*)(As + (r*256 + wave*64)*8));
      async_cp16(Bm + (long long)(nBase+row)*ldb + k0 + col, (void*)(Bs + (r*256 + wave*64)*8));
    }
    __syncthreads();
    bf16x8 af[4], bfr[4];
    #pragma unroll
    for (int i=0;i<4;i++){
      af[i]  = *(const bf16x8*)(As + (wm + i*16 + lc)*32 + quad*8);
      bfr[i] = *(const bf16x8*)(Bs + (wn + i*16 + lc)*32 + quad*8);
    }
    #pragma unroll
    for (int i=0;i<4;i++)
      #pragma unroll
      for (int j=0;j<4;j++)
        acc[i][j] = __builtin_amdgcn_mfma_f32_16x16x32_bf16(af[i], bfr[j], acc[i][j], 0,0,0);
    __syncthreads();
  }
  // epilogue: C/D layout col=lane&15, row=quad*4+e (m89/m91 verified)
  #pragma unroll
  for (int i=0;i<4;i++){
    #pragma unroll
    for (int j=0;j<4;j++){
      int colG = nBase + wn + j*16 + lc;
      float bc = (biasMode==0) ? bias[colG] : 0.0f;
      #pragma unroll
      for (int e=0;e<4;e++){
        int rowG = mBase + wm + i*16 + quad*4 + e;
        float val = acc[i][j][e] + ((biasMode==0) ? bc : bias[rowG]);
        C[(long long)rowG*ldc + colG] = f2bf(val);
      }
    }
  }
}

// -------------------------------------------- attention scores + softmax
// Per block: 64 t-rows, iterate s-tiles (128 wide) up to the diagonal.
// Two passes: (0) online row max/sum, (1) recompute + write normalized bf16 P.
// Mask quirk: s>t OR score==0 -> -10000 (exp underflows to exact 0, = ref).
__global__ __launch_bounds__(256, 2)
void attn_kernel(const u16* __restrict__ qp, const u16* __restrict__ kp,
                 u16* __restrict__ P)
{
  __shared__ __align__(16) u16 Qs[64*32];
  __shared__ __align__(16) u16 Ks[128*32];
  int tid = threadIdx.x, lane = tid & 63, wave = tid >> 6;
  int idx = blockIdx.x;
  int t64 = 31 - (idx >> 4);       // heavy tiles dispatch first
  int b = idx & 15;
  int tBase = t64 * 64;
  int numS = (tBase >> 7) + 1;
  const u16* Q  = qp + ((long long)b*T_ + tBase) * R_;
  const u16* Kb = kp + (long long)b*T_*R_;
  u16* Pb = P + (long long)b*T_*T_;
  const float scale = 0.0625f;     // 1/sqrt(256)
  int quad = lane >> 4, lc = lane & 15;
  int rowLoc = wave*16 + quad*4;

  float m_[4], l_[4], rl[4];
  #pragma unroll
  for (int e=0;e<4;e++){ m_[e] = -3.0e38f; l_[e] = 0.0f; rl[e] = 0.0f; }

  for (int pass=0; pass<2; pass++){
    if (pass==1){
      #pragma unroll
      for (int e=0;e<4;e++) rl[e] = 1.0f / l_[e];
    }
    for (int sT=0; sT<numS; sT++){
      f32x4 acc[8];
      #pragma unroll
      for (int j=0;j<8;j++) acc[j] = (f32x4){0.f,0.f,0.f,0.f};
      const u16* Kt = Kb + (long long)sT*128*R_;
      for (int k0=0;k0<R_;k0+=32){
        {
          int row = tid >> 2, col = (tid & 3)*8;
          async_cp16(Q + (long long)row*R_ + k0 + col, (void*)(Qs + (wave*64)*8));
        }
        #pragma unroll
        for (int r=0;r<2;r++){
          int c = r*256 + tid;
          int row = c >> 2, col = (c & 3)*8;
          async_cp16(Kt + (long long)row*R_ + k0 + col, (void*)(Ks + (r*256 + wave*64)*8));
        }
        __syncthreads();
        bf16x8 aq = *(const bf16x8*)(Qs + (wave*16 + lc)*32 + quad*8);
        #pragma unroll
        for (int j=0;j<8;j++){
          bf16x8 bk = *(const bf16x8*)(Ks + (j*16 + lc)*32 + quad*8);
          acc[j] = __builtin_amdgcn_mfma_f32_16x16x32_bf16(aq, bk, acc[j], 0,0,0);
        }
        __syncthreads();
      }
      int sCol0 = sT*128 + lc;
      if (pass==0){
        #pragma unroll
        for (int e=0;e<4;e++){
          int t = tBase + rowLoc + e;
          float vals[8];
          float tmax = -3.0e38f;
          #pragma unroll
          for (int j=0;j<8;j++){
            float v = acc[j][e] * scale;
            int s = sCol0 + j*16;
            if (s > t || v == 0.0f) v = -10000.0f;
            vals[j] = v;
            tmax = fmaxf(tmax, v);
          }
          #pragma unroll
          for (int off=1; off<16; off<<=1)
            tmax = fmaxf(tmax, __shfl_xor(tmax, off, 64));
          float mn = fmaxf(m_[e], tmax);
          float ps = 0.0f;
          #pragma unroll
          for (int j=0;j<8;j++) ps += __expf(vals[j] - mn);
          #pragma unroll
          for (int off=1; off<16; off<<=1)
            ps += __shfl_xor(ps, off, 64);
          l_[e] = l_[e]*__expf(m_[e]-mn) + ps;
          m_[e] = mn;
        }
      } else {
        #pragma unroll
        for (int e=0;e<4;e++){
          int t = tBase + rowLoc + e;
          long long ro = (long long)t * T_;
          #pragma unroll
          for (int j=0;j<8;j++){
            float v = acc[j][e]*scale;
            int s = sCol0 + j*16;
            if (s > t || v == 0.0f) v = -10000.0f;
            float p = __expf(v - m_[e]) * rl[e];
            Pb[ro + s] = f2bf(p);
          }
        }
      }
    }
  }
}

// --------------------------------------------------------------- PV GEMM
// out[b][n][t][r] = sum_s P[b][t][s] * VT[b][n*256+r][s]; K limited to t0+128
// (P diagonal tile holds exact zeros above the diagonal; tiles beyond are
// never written and never read).
__global__ __launch_bounds__(256, 2)
void pv_kernel(const u16* __restrict__ P, const u16* __restrict__ VT,
               float* __restrict__ out)
{
  __shared__ __align__(16) u16 As[128*32];
  __shared__ __align__(16) u16 Bs[128*32];
  int tid = threadIdx.x, lane = tid & 63, wave = tid >> 6;
  int jBase = blockIdx.x * 128;
  int tTile = 15 - blockIdx.y;     // heavy-first
  int b = blockIdx.z;
  int t0 = tTile * 128;
  int K = t0 + 128;
  const u16* A  = P  + (long long)b*T_*T_ + (long long)t0*T_;
  const u16* Bm = VT + (long long)b*1024*T_ + (long long)jBase*T_;
  int wm = (wave>>1)*64, wn = (wave&1)*64;
  int quad = lane>>4, lc = lane&15;

  f32x4 acc[4][4];
  #pragma unroll
  for (int i=0;i<4;i++)
    #pragma unroll
    for (int j=0;j<4;j++) acc[i][j] = (f32x4){0.f,0.f,0.f,0.f};

  for (int k0=0; k0<K; k0+=32){
    #pragma unroll
    for (int r=0;r<2;r++){
      int c = r*256 + tid;
      int row = c >> 2, col = (c & 3)*8;
      async_cp16(A  + (long long)row*T_ + k0 + col, (void*)(As + (r*256 + wave*64)*8));
      async_cp16(Bm + (long long)row*T_ + k0 + col, (void*)(Bs + (r*256 + wave*64)*8));
    }
    __syncthreads();
    bf16x8 af[4], bfr[4];
    #pragma unroll
    for (int i=0;i<4;i++){
      af[i]  = *(const bf16x8*)(As + (wm + i*16 + lc)*32 + quad*8);
      bfr[i] = *(const bf16x8*)(Bs + (wn + i*16 + lc)*32 + quad*8);
    }
    #pragma unroll
    for (int i=0;i<4;i++)
      #pragma unroll
      for (int j=0;j<4;j++)
        acc[i][j] = __builtin_amdgcn_mfma_f32_16x16x32_bf16(af[i], bfr[j], acc[i][j], 0,0,0);
    __syncthreads();
  }
  #pragma unroll
  for (int i=0;i<4;i++){
    #pragma unroll
    for (int j=0;j<4;j++){
      int colJ = jBase + wn + j*16 + lc;
      int n = colJ >> 8, r = colJ & 255;
      #pragma unroll
      for (int e=0;e<4;e++){
        int t = t0 + wm + i*16 + quad*4 + e;
        out[(((long long)b*NS_ + n)*T_ + t)*R_ + r] = acc[i][j][e];
      }
    }
  }
}

// ------------------------------------------------------------------ proj
// proj[b][n][t] = sum_o VT[b][n*256+o][t] * wp[o] + bp  (coalesced over t)
__global__ __launch_bounds__(256)
void proj_kernel(const u16* __restrict__ VT, const float* __restrict__ wp,
                 const float* __restrict__ bp, float* __restrict__ proj){
  int gid = blockIdx.x*256 + threadIdx.x;   // 16*4*2048
  int bn = gid >> 11, t = gid & 2047;
  const u16* base = VT + (long long)bn*R_*T_ + t;
  float acc = bp[0];
  #pragma unroll 8
  for (int o=0;o<R_;o++)
    acc = fmaf(bf2f(base[(long long)o*T_]), wp[o], acc);
  proj[gid] = acc;
}

// ------------------------------------------------------------- cov + loss
__global__ __launch_bounds__(256)
void loss_kernel(const float* __restrict__ proj, float* __restrict__ simOut){
  __shared__ float red[256];
  int tid = threadIdx.x;
  float sim = 0.0f;
  for (int b=0;b<B_;b++){
    const float* pb = proj + b*NS_*T_;
    float s1[4] = {0,0,0,0};
    float s2[10] = {0,0,0,0,0,0,0,0,0,0};
    for (int t=tid; t<T_; t+=256){
      float x0 = pb[0*T_+t], x1 = pb[1*T_+t], x2 = pb[2*T_+t], x3 = pb[3*T_+t];
      s1[0]+=x0; s1[1]+=x1; s1[2]+=x2; s1[3]+=x3;
      s2[0]+=x0*x0; s2[1]+=x1*x0; s2[2]+=x1*x1; s2[3]+=x2*x0; s2[4]+=x2*x1;
      s2[5]+=x2*x2; s2[6]+=x3*x0; s2[7]+=x3*x1; s2[8]+=x3*x2; s2[9]+=x3*x3;
    }
    float tot[14];
    for (int kk=0; kk<14; kk++){
      red[tid] = (kk<4) ? s1[kk] : s2[kk-4];
      __syncthreads();
      for (int s=128; s>0; s>>=1){ if (tid<s) red[tid] += red[tid+s]; __syncthreads(); }
      tot[kk] = red[0];
      __syncthreads();
    }
    const float invT  = 1.0f/(float)T_;
    const float invT1 = 1.0f/(float)(T_-1);
    float csum = 0.0f;
    for (int n=0;n<4;n++){
      for (int m=0;m<=n;m++){
        int id = n*(n+1)/2 + m;
        float c = (tot[4+id] - tot[n]*tot[m]*invT) * invT1;
        csum += (n==m) ? fabsf(c) : 2.0f*fabsf(c);
      }
    }
    sim += 0.5f*csum;
  }
  if (tid==0) simOut[0] = sim * (1.0f/(float)B_);
}

// ----------------------------------------------------------------- launch
extern "C" void kernel_launch(void* const* d_in, const int* in_sizes, int n_in,
                              void* d_out, int out_size, void* d_ws, size_t ws_size,
                              hipStream_t stream)
{
  const float* q  = (const float*)d_in[0];
  const float* k  = (const float*)d_in[1];
  const float* v  = (const float*)d_in[2];
  const float* wq = (const float*)d_in[3];
  const float* bq = (const float*)d_in[4];
  const float* wk = (const float*)d_in[5];
  const float* bk = (const float*)d_in[6];
  const float* wv = (const float*)d_in[7];
  const float* bv = (const float*)d_in[8];
  const float* wp = (const float*)d_in[9];
  const float* bp = (const float*)d_in[10];
  float* out = (float*)d_out;

  // workspace layout (bytes); total ~286.6 MB
  char* ws = (char*)d_ws;
  u16* qbf   = (u16*)(ws + 0);          // 16 MB  [B*T][R] bf16
  u16* kbf   = (u16*)(ws + 16777216);   // 16 MB
  u16* vbf   = (u16*)(ws + 33554432);   // 16 MB
  u16* wqbf  = (u16*)(ws + 50331648);   // 128 KB
  u16* wkbf  = (u16*)(ws + 50462720);   // 128 KB
  u16* wvbf  = (u16*)(ws + 50593792);   // 512 KB
  u16* qpbf  = (u16*)(ws + 51118080);   // 16 MB  [B*T][R] bf16
  u16* kpbf  = (u16*)(ws + 67895296);   // 16 MB
  u16* vtbf  = (u16*)(ws + 84672512);   // 64 MB  [B][NS*R][T] bf16 (vs^T, +bias)
  u16* pbuf  = (u16*)(ws + 151781376);  // 128 MB [B][T][T] bf16 (attn probs)
  float* prj = (float*)(ws + 285999104);// 512 KB [B][NS][T] f32

  // 0) fp32 -> bf16 conversions
  cvt_kernel<<<8192,256,0,stream>>>(q,  qbf, 2097152);
  cvt_kernel<<<8192,256,0,stream>>>(k,  kbf, 2097152);
  cvt_kernel<<<8192,256,0,stream>>>(v,  vbf, 2097152);
  cvt_kernel<<<64,  256,0,stream>>>(wq, wqbf, 16384);
  cvt_kernel<<<64,  256,0,stream>>>(wk, wkbf, 16384);
  cvt_kernel<<<256, 256,0,stream>>>(wv, wvbf, 65536);

  // 1) projections: qp = q@wq^T+bq, kp = k@wk^T+bk  (M=32768,N=256,K=256)
  dim3 gq(2,256,1);
  gemm_nt_bias<<<gq,256,0,stream>>>(qbf, wqbf, qpbf, bq, 256,256,256,256, 0,0,0, 0, 0);
  gemm_nt_bias<<<gq,256,0,stream>>>(kbf, wkbf, kpbf, bk, 256,256,256,256, 0,0,0, 0, 0);
  // vs^T: per (b,n): C[o][t] = wv[n] @ v[b]^T + bv[n]  (M=256,N=2048,K=256)
  dim3 gv(16,2,64);
  gemm_nt_bias<<<gv,256,0,stream>>>(wvbf, vbf, vtbf, bv, 256,256,2048,256,
                                    65536LL, 524288LL, 524288LL, 256, 1);

  // 2) causal softmax -> P (bf16, normalized)
  attn_kernel<<<512,256,0,stream>>>(qpbf, kpbf, pbuf);

  // 3) out = P @ Vcat
  dim3 gp(8,16,16);
  pv_kernel<<<gp,256,0,stream>>>(pbuf, vtbf, out);

  // 4) sim loss
  proj_kernel<<<512,256,0,stream>>>(vtbf, wp, bp, prj);
  loss_kernel<<<1,256,0,stream>>>(prj, out + 33554432);
}

// Round 2
// 620.170 us; speedup vs baseline: 1.2636x; 1.2636x over previous
//
#include <hip/hip_runtime.h>

#define B_  16
#define T_  2048
#define R_  256
#define NS_ 4

typedef unsigned short u16;
typedef __attribute__((ext_vector_type(8))) __bf16 bf16x8;
typedef __attribute__((ext_vector_type(4))) float f32x4;

__device__ __forceinline__ u16 f2bf(float f){
  union { float f; unsigned u; } x; x.f = f;
  unsigned r = x.u + 0x7FFFu + ((x.u >> 16) & 1u);
  return (u16)(r >> 16);
}
__device__ __forceinline__ float bf2f(u16 h){
  union { unsigned u; float f; } x; x.u = ((unsigned)h) << 16; return x.f;
}

// async global->LDS, 16B per lane. LDS dest must be wave-uniform base; HW
// writes lane i at base + i*16 (guide §5). Our chunk order matches that.
__device__ __forceinline__ void async_cp16(const void* g, void* l){
  __builtin_amdgcn_global_load_lds((__attribute__((address_space(1))) void*)g,
                                   (__attribute__((address_space(3))) void*)l,
                                   16, 0, 0);
}

// ---------------------------------------------------------------- convert
__global__ __launch_bounds__(256)
void cvt_kernel(const float* __restrict__ src, u16* __restrict__ dst, int n4){
  int i = blockIdx.x*256 + threadIdx.x;
  if (i >= n4) return;
  float4 f = ((const float4*)src)[i];
  ushort4 o;
  o.x = f2bf(f.x); o.y = f2bf(f.y); o.z = f2bf(f.z); o.w = f2bf(f.w);
  ((ushort4*)dst)[i] = o;
}

// ------------------------------------------------- generic NT GEMM (bf16)
// C[m][n] = sum_k A[m][k]*B[n][k] + bias ; C stored bf16.
// z decode: n = z&3 (weight/bias select), b = z>>2 (batch select).
// biasMode 0: bias indexed by col (N). biasMode 1: bias indexed by row (M).
__global__ __launch_bounds__(256, 2)
void gemm_nt_bias(const u16* __restrict__ A, const u16* __restrict__ Bm,
                  u16* __restrict__ C, const float* __restrict__ bias,
                  int lda, int ldb, int ldc, int K,
                  long long sAn, long long sBb, long long sCz,
                  int sBiasN, int biasMode)
{
  __shared__ __align__(16) u16 As[128*32];
  __shared__ __align__(16) u16 Bs[128*32];
  int tid = threadIdx.x;
  int lane = tid & 63, wave = tid >> 6;
  int z = blockIdx.z;
  int nIdx = z & 3, bIdx = z >> 2;
  A    += (long long)nIdx * sAn;
  Bm   += (long long)bIdx * sBb;
  C    += (long long)z * sCz;
  bias += (long long)nIdx * sBiasN;
  int mBase = blockIdx.y * 128;
  int nBase = blockIdx.x * 128;
  int wm = (wave >> 1) * 64, wn = (wave & 1) * 64;
  int quad = lane >> 4, lc = lane & 15;

  f32x4 acc[4][4];
  #pragma unroll
  for (int i=0;i<4;i++)
    #pragma unroll
    for (int j=0;j<4;j++) acc[i][j] = (f32x4){0.f,0.f,0.f,0.f};

  for (int k0=0; k0<K; k0+=32){
    #pragma unroll
    for (int r=0;r<2;r++){
      int c = r*256 + tid;
      int row = c >> 2, col = (c & 3)*8;
      async_cp16(A  + (long long)(mBase+row)*lda + k0 + col, (void*)(As + (r*256 + wave*64)*8));
      async_cp16(Bm + (long long)(nBase+row)*ldb + k0 + col, (void*)(Bs + (r*256 + wave*64)*8));
    }
    __syncthreads();
    bf16x8 af[4], bfr[4];
    #pragma unroll
    for (int i=0;i<4;i++){
      af[i]  = *(const bf16x8*)(As + (wm + i*16 + lc)*32 + quad*8);
      bfr[i] = *(const bf16x8*)(Bs + (wn + i*16 + lc)*32 + quad*8);
    }
    #pragma unroll
    for (int i=0;i<4;i++)
      #pragma unroll
      for (int j=0;j<4;j++)
        acc[i][j] = __builtin_amdgcn_mfma_f32_16x16x32_bf16(af[i], bfr[j], acc[i][j], 0,0,0);
    __syncthreads();
  }
  // epilogue: C/D layout col=lane&15, row=quad*4+e (m89/m91 verified)
  #pragma unroll
  for (int i=0;i<4;i++){
    #pragma unroll
    for (int j=0;j<4;j++){
      int colG = nBase + wn + j*16 + lc;
      float bc = (biasMode==0) ? bias[colG] : 0.0f;
      #pragma unroll
      for (int e=0;e<4;e++){
        int rowG = mBase + wm + i*16 + quad*4 + e;
        float val = acc[i][j][e] + ((biasMode==0) ? bc : bias[rowG]);
        C[(long long)rowG*ldc + colG] = f2bf(val);
      }
    }
  }
}

// -------------------------------------------- attention scores + softmax
// Per block: 64 t-rows, iterate s-tiles (128 wide) up to the diagonal.
// Two passes: (0) online row max/sum, (1) recompute + write normalized bf16 P.
// Mask quirk: s>t OR score==0 -> -10000 (exp underflows to exact 0, = ref).
__global__ __launch_bounds__(256, 2)
void attn_kernel(const u16* __restrict__ qp, const u16* __restrict__ kp,
                 u16* __restrict__ P)
{
  __shared__ __align__(16) u16 Qs[64*32];
  __shared__ __align__(16) u16 Ks[128*32];
  int tid = threadIdx.x, lane = tid & 63, wave = tid >> 6;
  int idx = blockIdx.x;
  int t64 = 31 - (idx >> 4);       // heavy tiles dispatch first
  int b = idx & 15;
  int tBase = t64 * 64;
  int numS = (tBase >> 7) + 1;
  const u16* Q  = qp + ((long long)b*T_ + tBase) * R_;
  const u16* Kb = kp + (long long)b*T_*R_;
  u16* Pb = P + (long long)b*T_*T_;
  const float scale = 0.0625f;     // 1/sqrt(256)
  int quad = lane >> 4, lc = lane & 15;
  int rowLoc = wave*16 + quad*4;

  float m_[4], l_[4], rl[4];
  #pragma unroll
  for (int e=0;e<4;e++){ m_[e] = -3.0e38f; l_[e] = 0.0f; rl[e] = 0.0f; }

  for (int pass=0; pass<2; pass++){
    if (pass==1){
      #pragma unroll
      for (int e=0;e<4;e++) rl[e] = 1.0f / l_[e];
    }
    for (int sT=0; sT<numS; sT++){
      f32x4 acc[8];
      #pragma unroll
      for (int j=0;j<8;j++) acc[j] = (f32x4){0.f,0.f,0.f,0.f};
      const u16* Kt = Kb + (long long)sT*128*R_;
      for (int k0=0;k0<R_;k0+=32){
        {
          int row = tid >> 2, col = (tid & 3)*8;
          async_cp16(Q + (long long)row*R_ + k0 + col, (void*)(Qs + (wave*64)*8));
        }
        #pragma unroll
        for (int r=0;r<2;r++){
          int c = r*256 + tid;
          int row = c >> 2, col = (c & 3)*8;
          async_cp16(Kt + (long long)row*R_ + k0 + col, (void*)(Ks + (r*256 + wave*64)*8));
        }
        __syncthreads();
        bf16x8 aq = *(const bf16x8*)(Qs + (wave*16 + lc)*32 + quad*8);
        #pragma unroll
        for (int j=0;j<8;j++){
          bf16x8 bk = *(const bf16x8*)(Ks + (j*16 + lc)*32 + quad*8);
          acc[j] = __builtin_amdgcn_mfma_f32_16x16x32_bf16(aq, bk, acc[j], 0,0,0);
        }
        __syncthreads();
      }
      int sCol0 = sT*128 + lc;
      if (pass==0){
        #pragma unroll
        for (int e=0;e<4;e++){
          int t = tBase + rowLoc + e;
          float vals[8];
          float tmax = -3.0e38f;
          #pragma unroll
          for (int j=0;j<8;j++){
            float v = acc[j][e] * scale;
            int s = sCol0 + j*16;
            if (s > t || v == 0.0f) v = -10000.0f;
            vals[j] = v;
            tmax = fmaxf(tmax, v);
          }
          #pragma unroll
          for (int off=1; off<16; off<<=1)
            tmax = fmaxf(tmax, __shfl_xor(tmax, off, 64));
          float mn = fmaxf(m_[e], tmax);
          float ps = 0.0f;
          #pragma unroll
          for (int j=0;j<8;j++) ps += __expf(vals[j] - mn);
          #pragma unroll
          for (int off=1; off<16; off<<=1)
            ps += __shfl_xor(ps, off, 64);
          l_[e] = l_[e]*__expf(m_[e]-mn) + ps;
          m_[e] = mn;
        }
      } else {
        #pragma unroll
        for (int e=0;e<4;e++){
          int t = tBase + rowLoc + e;
          long long ro = (long long)t * T_;
          #pragma unroll
          for (int j=0;j<8;j++){
            float v = acc[j][e]*scale;
            int s = sCol0 + j*16;
            if (s > t || v == 0.0f) v = -10000.0f;
            float p = __expf(v - m_[e]) * rl[e];
            Pb[ro + s] = f2bf(p);
          }
        }
      }
    }
  }
}

// --------------------------------------------------------------- PV GEMM
// out[b][n][t][r] = sum_s P[b][t][s] * VT[b][n*256+r][s]; K limited to t0+128
// (P diagonal tile holds exact zeros above the diagonal; tiles beyond are
// never written and never read).
__global__ __launch_bounds__(256, 2)
void pv_kernel(const u16* __restrict__ P, const u16* __restrict__ VT,
               float* __restrict__ out)
{
  __shared__ __align__(16) u16 As[128*32];
  __shared__ __align__(16) u16 Bs[128*32];
  int tid = threadIdx.x, lane = tid & 63, wave = tid >> 6;
  int jBase = blockIdx.x * 128;
  int tTile = 15 - blockIdx.y;     // heavy-first
  int b = blockIdx.z;
  int t0 = tTile * 128;
  int K = t0 + 128;
  const u16* A  = P  + (long long)b*T_*T_ + (long long)t0*T_;
  const u16* Bm = VT + (long long)b*1024*T_ + (long long)jBase*T_;
  int wm = (wave>>1)*64, wn = (wave&1)*64;
  int quad = lane>>4, lc = lane&15;

  f32x4 acc[4][4];
  #pragma unroll
  for (int i=0;i<4;i++)
    #pragma unroll
    for (int j=0;j<4;j++) acc[i][j] = (f32x4){0.f,0.f,0.f,0.f};

  for (int k0=0; k0<K; k0+=32){
    #pragma unroll
    for (int r=0;r<2;r++){
      int c = r*256 + tid;
      int row = c >> 2, col = (c & 3)*8;
      async_cp16(A  + (long long)row*T_ + k0 + col, (void*)(As + (r*256 + wave*64)*8));
      async_cp16(Bm + (long long)row*T_ + k0 + col, (void*)(Bs + (r*256 + wave*64)*8));
    }
    __syncthreads();
    bf16x8 af[4], bfr[4];
    #pragma unroll
    for (int i=0;i<4;i++){
      af[i]  = *(const bf16x8*)(As + (wm + i*16 + lc)*32 + quad*8);
      bfr[i] = *(const bf16x8*)(Bs + (wn + i*16 + lc)*32 + quad*8);
    }
    #pragma unroll
    for (int i=0;i<4;i++)
      #pragma unroll
      for (int j=0;j<4;j++)
        acc[i][j] = __builtin_amdgcn_mfma_f32_16x16x32_bf16(af[i], bfr[j], acc[i][j], 0,0,0);
    __syncthreads();
  }
  #pragma unroll
  for (int i=0;i<4;i++){
    #pragma unroll
    for (int j=0;j<4;j++){
      int colJ = jBase + wn + j*16 + lc;
      int n = colJ >> 8, r = colJ & 255;
      #pragma unroll
      for (int e=0;e<4;e++){
        int t = t0 + wm + i*16 + quad*4 + e;
        out[(((long long)b*NS_ + n)*T_ + t)*R_ + r] = acc[i][j][e];
      }
    }
  }
}

// ------------------------------------------------------------------ proj
// proj[b][n][t] = sum_o VT[b][n*256+o][t] * wp[o] + bp  (coalesced over t)
__global__ __launch_bounds__(256)
void proj_kernel(const u16* __restrict__ VT, const float* __restrict__ wp,
                 const float* __restrict__ bp, float* __restrict__ proj){
  int gid = blockIdx.x*256 + threadIdx.x;   // 16*4*2048
  int bn = gid >> 11, t = gid & 2047;
  const u16* base = VT + (long long)bn*R_*T_ + t;
  float acc = bp[0];
  #pragma unroll 8
  for (int o=0;o<R_;o++)
    acc = fmaf(bf2f(base[(long long)o*T_]), wp[o], acc);
  proj[gid] = acc;
}

// ------------------------------------------------------- cov + loss (R2:
// parallel: one block per batch, shuffle-reduce, partials -> final sum)
__global__ __launch_bounds__(256)
void loss_batch_kernel(const float* __restrict__ proj, float* __restrict__ partial){
  __shared__ float red[4][14];
  int tid = threadIdx.x, lane = tid & 63, wave = tid >> 6;
  int b = blockIdx.x;
  const float* pb = proj + b*NS_*T_;
  float s[14];
  #pragma unroll
  for (int kk=0;kk<14;kk++) s[kk]=0.0f;
  for (int t=tid; t<T_; t+=256){
    float x0 = pb[0*T_+t], x1 = pb[1*T_+t], x2 = pb[2*T_+t], x3 = pb[3*T_+t];
    s[0]+=x0; s[1]+=x1; s[2]+=x2; s[3]+=x3;
    s[4]+=x0*x0; s[5]+=x1*x0; s[6]+=x1*x1; s[7]+=x2*x0; s[8]+=x2*x1;
    s[9]+=x2*x2; s[10]+=x3*x0; s[11]+=x3*x1; s[12]+=x3*x2; s[13]+=x3*x3;
  }
  // per-wave butterfly reduction (no barriers)
  #pragma unroll
  for (int kk=0;kk<14;kk++){
    #pragma unroll
    for (int off=1; off<64; off<<=1)
      s[kk] += __shfl_xor(s[kk], off, 64);
  }
  if (lane == 0){
    #pragma unroll
    for (int kk=0;kk<14;kk++) red[wave][kk] = s[kk];
  }
  __syncthreads();
  if (tid == 0){
    float tot[14];
    #pragma unroll
    for (int kk=0;kk<14;kk++)
      tot[kk] = red[0][kk] + red[1][kk] + red[2][kk] + red[3][kk];
    const float invT  = 1.0f/(float)T_;
    const float invT1 = 1.0f/(float)(T_-1);
    float csum = 0.0f;
    #pragma unroll
    for (int n=0;n<4;n++){
      #pragma unroll
      for (int m=0;m<=n;m++){
        int id = n*(n+1)/2 + m;
        float c = (tot[4+id] - tot[n]*tot[m]*invT) * invT1;
        csum += (n==m) ? fabsf(c) : 2.0f*fabsf(c);
      }
    }
    partial[b] = 0.5f*csum;
  }
}

__global__ void loss_final_kernel(const float* __restrict__ partial,
                                  float* __restrict__ simOut){
  if (threadIdx.x == 0){
    float sim = 0.0f;
    #pragma unroll
    for (int b=0;b<B_;b++) sim += partial[b];
    simOut[0] = sim * (1.0f/(float)B_);
  }
}

// ----------------------------------------------------------------- launch
extern "C" void kernel_launch(void* const* d_in, const int* in_sizes, int n_in,
                              void* d_out, int out_size, void* d_ws, size_t ws_size,
                              hipStream_t stream)
{
  const float* q  = (const float*)d_in[0];
  const float* k  = (const float*)d_in[1];
  const float* v  = (const float*)d_in[2];
  const float* wq = (const float*)d_in[3];
  const float* bq = (const float*)d_in[4];
  const float* wk = (const float*)d_in[5];
  const float* bk = (const float*)d_in[6];
  const float* wv = (const float*)d_in[7];
  const float* bv = (const float*)d_in[8];
  const float* wp = (const float*)d_in[9];
  const float* bp = (const float*)d_in[10];
  float* out = (float*)d_out;

  // workspace layout (bytes); total ~286.6 MB
  char* ws = (char*)d_ws;
  u16* qbf   = (u16*)(ws + 0);          // 16 MB  [B*T][R] bf16 (dead after proj GEMMs)
  u16* kbf   = (u16*)(ws + 16777216);   // 16 MB
  u16* vbf   = (u16*)(ws + 33554432);   // 16 MB
  u16* wqbf  = (u16*)(ws + 50331648);   // 128 KB
  u16* wkbf  = (u16*)(ws + 50462720);   // 128 KB
  u16* wvbf  = (u16*)(ws + 50593792);   // 512 KB
  u16* qpbf  = (u16*)(ws + 51118080);   // 16 MB  [B*T][R] bf16
  u16* kpbf  = (u16*)(ws + 67895296);   // 16 MB
  u16* vtbf  = (u16*)(ws + 84672512);   // 64 MB  [B][NS*R][T] bf16 (vs^T, +bias)
  u16* pbuf  = (u16*)(ws + 151781376);  // 128 MB [B][T][T] bf16 (attn probs)
  float* prj = (float*)(ws + 285999104);// 512 KB [B][NS][T] f32
  float* lpart = (float*)(ws + 0);      // 64 B, reuses dead qbf region

  // 0) fp32 -> bf16 conversions
  cvt_kernel<<<8192,256,0,stream>>>(q,  qbf, 2097152);
  cvt_kernel<<<8192,256,0,stream>>>(k,  kbf, 2097152);
  cvt_kernel<<<8192,256,0,stream>>>(v,  vbf, 2097152);
  cvt_kernel<<<64,  256,0,stream>>>(wq, wqbf, 16384);
  cvt_kernel<<<64,  256,0,stream>>>(wk, wkbf, 16384);
  cvt_kernel<<<256, 256,0,stream>>>(wv, wvbf, 65536);

  // 1) projections: qp = q@wq^T+bq, kp = k@wk^T+bk  (M=32768,N=256,K=256)
  dim3 gq(2,256,1);
  gemm_nt_bias<<<gq,256,0,stream>>>(qbf, wqbf, qpbf, bq, 256,256,256,256, 0,0,0, 0, 0);
  gemm_nt_bias<<<gq,256,0,stream>>>(kbf, wkbf, kpbf, bk, 256,256,256,256, 0,0,0, 0, 0);
  // vs^T: per (b,n): C[o][t] = wv[n] @ v[b]^T + bv[n]  (M=256,N=2048,K=256)
  dim3 gv(16,2,64);
  gemm_nt_bias<<<gv,256,0,stream>>>(wvbf, vbf, vtbf, bv, 256,256,2048,256,
                                    65536LL, 524288LL, 524288LL, 256, 1);

  // 2) causal softmax -> P (bf16, normalized)
  attn_kernel<<<512,256,0,stream>>>(qpbf, kpbf, pbuf);

  // 3) out = P @ Vcat
  dim3 gp(8,16,16);
  pv_kernel<<<gp,256,0,stream>>>(pbuf, vtbf, out);

  // 4) sim loss (proj -> per-batch cov partials -> final mean)
  proj_kernel<<<512,256,0,stream>>>(vtbf, wp, bp, prj);
  loss_batch_kernel<<<16,256,0,stream>>>(prj, lpart);
  loss_final_kernel<<<1,64,0,stream>>>(lpart, out + 33554432);
}

// Round 3
// 523.993 us; speedup vs baseline: 1.4955x; 1.1835x over previous
//
#include <hip/hip_runtime.h>

#define B_  16
#define T_  2048
#define R_  256
#define NS_ 4

typedef unsigned short u16;
typedef __attribute__((ext_vector_type(8))) __bf16 bf16x8;
typedef __attribute__((ext_vector_type(4))) float f32x4;

__device__ __forceinline__ u16 f2bf(float f){
  union { float f; unsigned u; } x; x.f = f;
  unsigned r = x.u + 0x7FFFu + ((x.u >> 16) & 1u);
  return (u16)(r >> 16);
}
__device__ __forceinline__ float bf2f(u16 h){
  union { unsigned u; float f; } x; x.u = ((unsigned)h) << 16; return x.f;
}

// async global->LDS, 16B per lane. LDS dest must be wave-uniform base; HW
// writes lane i at base + i*16 (guide §5). Our chunk order matches that.
__device__ __forceinline__ void async_cp16(const void* g, void* l){
  __builtin_amdgcn_global_load_lds((__attribute__((address_space(1))) void*)g,
                                   (__attribute__((address_space(3))) void*)l,
                                   16, 0, 0);
}

// ---------------------------------------------------------------- convert
__global__ __launch_bounds__(256)
void cvt_kernel(const float* __restrict__ src, u16* __restrict__ dst, int n4){
  int i = blockIdx.x*256 + threadIdx.x;
  if (i >= n4) return;
  float4 f = ((const float4*)src)[i];
  ushort4 o;
  o.x = f2bf(f.x); o.y = f2bf(f.y); o.z = f2bf(f.z); o.w = f2bf(f.w);
  ((ushort4*)dst)[i] = o;
}

__global__ __launch_bounds__(256)
void zero_kernel(float* __restrict__ p, int n){
  int i = blockIdx.x*256 + threadIdx.x;
  if (i < n) p[i] = 0.0f;
}

// ------------------------------------------------- generic NT GEMM (bf16)
// C[m][n] = sum_k A[m][k]*B[n][k] + bias ; C stored bf16.
// z decode: n = z&3 (weight/bias select), b = z>>2 (batch select).
// biasMode 0: bias indexed by col (N). biasMode 1: bias indexed by row (M).
__global__ __launch_bounds__(256, 2)
void gemm_nt_bias(const u16* __restrict__ A, const u16* __restrict__ Bm,
                  u16* __restrict__ C, const float* __restrict__ bias,
                  int lda, int ldb, int ldc, int K,
                  long long sAn, long long sBb, long long sCz,
                  int sBiasN, int biasMode)
{
  __shared__ __align__(16) u16 As[128*32];
  __shared__ __align__(16) u16 Bs[128*32];
  int tid = threadIdx.x;
  int lane = tid & 63, wave = tid >> 6;
  int z = blockIdx.z;
  int nIdx = z & 3, bIdx = z >> 2;
  A    += (long long)nIdx * sAn;
  Bm   += (long long)bIdx * sBb;
  C    += (long long)z * sCz;
  bias += (long long)nIdx * sBiasN;
  int mBase = blockIdx.y * 128;
  int nBase = blockIdx.x * 128;
  int wm = (wave >> 1) * 64, wn = (wave & 1) * 64;
  int quad = lane >> 4, lc = lane & 15;

  f32x4 acc[4][4];
  #pragma unroll
  for (int i=0;i<4;i++)
    #pragma unroll
    for (int j=0;j<4;j++) acc[i][j] = (f32x4){0.f,0.f,0.f,0.f};

  for (int k0=0; k0<K; k0+=32){
    #pragma unroll
    for (int r=0;r<2;r++){
      int c = r*256 + tid;
      int row = c >> 2, col = (c & 3)*8;
      async_cp16(A  + (long long)(mBase+row)*lda + k0 + col, (void*)(As + (r*256 + wave*64)*8));
      async_cp16(Bm + (long long)(nBase+row)*ldb + k0 + col, (void*)(Bs + (r*256 + wave*64)*8));
    }
    __syncthreads();
    bf16x8 af[4], bfr[4];
    #pragma unroll
    for (int i=0;i<4;i++){
      af[i]  = *(const bf16x8*)(As + (wm + i*16 + lc)*32 + quad*8);
      bfr[i] = *(const bf16x8*)(Bs + (wn + i*16 + lc)*32 + quad*8);
    }
    #pragma unroll
    for (int i=0;i<4;i++)
      #pragma unroll
      for (int j=0;j<4;j++)
        acc[i][j] = __builtin_amdgcn_mfma_f32_16x16x32_bf16(af[i], bfr[j], acc[i][j], 0,0,0);
    __syncthreads();
  }
  // epilogue: C/D layout col=lane&15, row=quad*4+e (m89/m91 verified)
  #pragma unroll
  for (int i=0;i<4;i++){
    #pragma unroll
    for (int j=0;j<4;j++){
      int colG = nBase + wn + j*16 + lc;
      float bc = (biasMode==0) ? bias[colG] : 0.0f;
      #pragma unroll
      for (int e=0;e<4;e++){
        int rowG = mBase + wm + i*16 + quad*4 + e;
        float val = acc[i][j][e] + ((biasMode==0) ? bc : bias[rowG]);
        C[(long long)rowG*ldc + colG] = f2bf(val);
      }
    }
  }
}

// ------------------------------------- attention scores, single sweep (R3)
// One block per (b, 64-row t-tile, 128-col s-tile). No max subtraction:
// scores here are bounded (|v| ~< 10 << 88), so p' = exp(v) is overflow-safe
// and softmax = p'/sum(p') exactly. Masked (s>t or v==0) -> exp(-10000) = 0
// in fp32, matching the reference tril+where quirk. Row sums accumulate via
// fp32 atomicAdd into l[B][T]; pv_kernel divides by l in its epilogue.
__global__ __launch_bounds__(256, 2)
void attn_kernel(const u16* __restrict__ qp, const u16* __restrict__ kp,
                 u16* __restrict__ P, float* __restrict__ lsum)
{
  __shared__ __align__(16) u16 Qs[64*32];
  __shared__ __align__(16) u16 Ks[128*32];
  int tid = threadIdx.x, lane = tid & 63, wave = tid >> 6;
  int b = blockIdx.y;
  // heavy-first flat decode: t64 descending, c(t64)=t64/2+1 s-tiles
  int f = blockIdx.x;
  int t64 = 31;
  while (f >= (t64 >> 1) + 1){ f -= (t64 >> 1) + 1; t64--; }
  int sT = f;
  int tBase = t64 * 64;
  const u16* Q  = qp + ((long long)b*T_ + tBase) * R_;
  const u16* Kt = kp + (long long)b*T_*R_ + (long long)sT*128*R_;
  u16* Pb = P + (long long)b*T_*T_;
  const float scale = 0.0625f;     // 1/sqrt(256)
  int quad = lane >> 4, lc = lane & 15;
  int rowLoc = wave*16 + quad*4;

  f32x4 acc[8];
  #pragma unroll
  for (int j=0;j<8;j++) acc[j] = (f32x4){0.f,0.f,0.f,0.f};

  for (int k0=0;k0<R_;k0+=32){
    {
      int row = tid >> 2, col = (tid & 3)*8;
      async_cp16(Q + (long long)row*R_ + k0 + col, (void*)(Qs + (wave*64)*8));
    }
    #pragma unroll
    for (int r=0;r<2;r++){
      int c = r*256 + tid;
      int row = c >> 2, col = (c & 3)*8;
      async_cp16(Kt + (long long)row*R_ + k0 + col, (void*)(Ks + (r*256 + wave*64)*8));
    }
    __syncthreads();
    bf16x8 aq = *(const bf16x8*)(Qs + (wave*16 + lc)*32 + quad*8);
    #pragma unroll
    for (int j=0;j<8;j++){
      bf16x8 bk = *(const bf16x8*)(Ks + (j*16 + lc)*32 + quad*8);
      acc[j] = __builtin_amdgcn_mfma_f32_16x16x32_bf16(aq, bk, acc[j], 0,0,0);
    }
    __syncthreads();
  }

  int sCol0 = sT*128 + lc;
  #pragma unroll
  for (int e=0;e<4;e++){
    int t = tBase + rowLoc + e;
    long long ro = (long long)t * T_;
    float rs = 0.0f;
    #pragma unroll
    for (int j=0;j<8;j++){
      float v = acc[j][e]*scale;
      int s = sCol0 + j*16;
      if (s > t || v == 0.0f) v = -10000.0f;
      float p = __expf(v);            // exact 0 when masked
      rs += p;
      Pb[ro + s] = f2bf(p);
    }
    // sum across the 16 lc-lanes of this quad (they hold cols of row t)
    #pragma unroll
    for (int off=1; off<16; off<<=1)
      rs += __shfl_xor(rs, off, 64);
    if (lc == 0)
      atomicAdd(&lsum[b*T_ + t], rs);
  }
}

// --------------------------------------------------------------- PV GEMM
// out[b][n][t][r] = (1/l[t]) * sum_s P'[b][t][s] * VT[b][n*256+r][s]
// K limited to t0+128 (P' diagonal tile holds exact zeros above the
// diagonal; tiles beyond are never written and never read).
__global__ __launch_bounds__(256, 2)
void pv_kernel(const u16* __restrict__ P, const u16* __restrict__ VT,
               const float* __restrict__ lsum, float* __restrict__ out)
{
  __shared__ __align__(16) u16 As[128*32];
  __shared__ __align__(16) u16 Bs[128*32];
  int tid = threadIdx.x, lane = tid & 63, wave = tid >> 6;
  int jBase = blockIdx.x * 128;
  int tTile = 15 - blockIdx.y;     // heavy-first
  int b = blockIdx.z;
  int t0 = tTile * 128;
  int K = t0 + 128;
  const u16* A  = P  + (long long)b*T_*T_ + (long long)t0*T_;
  const u16* Bm = VT + (long long)b*1024*T_ + (long long)jBase*T_;
  const float* lrow = lsum + b*T_;
  int wm = (wave>>1)*64, wn = (wave&1)*64;
  int quad = lane>>4, lc = lane&15;

  f32x4 acc[4][4];
  #pragma unroll
  for (int i=0;i<4;i++)
    #pragma unroll
    for (int j=0;j<4;j++) acc[i][j] = (f32x4){0.f,0.f,0.f,0.f};

  for (int k0=0; k0<K; k0+=32){
    #pragma unroll
    for (int r=0;r<2;r++){
      int c = r*256 + tid;
      int row = c >> 2, col = (c & 3)*8;
      async_cp16(A  + (long long)row*T_ + k0 + col, (void*)(As + (r*256 + wave*64)*8));
      async_cp16(Bm + (long long)row*T_ + k0 + col, (void*)(Bs + (r*256 + wave*64)*8));
    }
    __syncthreads();
    bf16x8 af[4], bfr[4];
    #pragma unroll
    for (int i=0;i<4;i++){
      af[i]  = *(const bf16x8*)(As + (wm + i*16 + lc)*32 + quad*8);
      bfr[i] = *(const bf16x8*)(Bs + (wn + i*16 + lc)*32 + quad*8);
    }
    #pragma unroll
    for (int i=0;i<4;i++)
      #pragma unroll
      for (int j=0;j<4;j++)
        acc[i][j] = __builtin_amdgcn_mfma_f32_16x16x32_bf16(af[i], bfr[j], acc[i][j], 0,0,0);
    __syncthreads();
  }
  #pragma unroll
  for (int i=0;i<4;i++){
    float rl[4];
    #pragma unroll
    for (int e=0;e<4;e++)
      rl[e] = __builtin_amdgcn_rcpf(lrow[t0 + wm + i*16 + quad*4 + e]);
    #pragma unroll
    for (int j=0;j<4;j++){
      int colJ = jBase + wn + j*16 + lc;
      int n = colJ >> 8, r = colJ & 255;
      #pragma unroll
      for (int e=0;e<4;e++){
        int t = t0 + wm + i*16 + quad*4 + e;
        out[(((long long)b*NS_ + n)*T_ + t)*R_ + r] = acc[i][j][e] * rl[e];
      }
    }
  }
}

// ------------------------------------------------------------------ proj
// proj[b][n][t] = sum_o VT[b][n*256+o][t] * wp[o] + bp  (coalesced over t)
__global__ __launch_bounds__(256)
void proj_kernel(const u16* __restrict__ VT, const float* __restrict__ wp,
                 const float* __restrict__ bp, float* __restrict__ proj){
  int gid = blockIdx.x*256 + threadIdx.x;   // 16*4*2048
  int bn = gid >> 11, t = gid & 2047;
  const u16* base = VT + (long long)bn*R_*T_ + t;
  float acc = bp[0];
  #pragma unroll 8
  for (int o=0;o<R_;o++)
    acc = fmaf(bf2f(base[(long long)o*T_]), wp[o], acc);
  proj[gid] = acc;
}

// ------------------------------------------------------- cov + loss
__global__ __launch_bounds__(256)
void loss_batch_kernel(const float* __restrict__ proj, float* __restrict__ partial){
  __shared__ float red[4][14];
  int tid = threadIdx.x, lane = tid & 63, wave = tid >> 6;
  int b = blockIdx.x;
  const float* pb = proj + b*NS_*T_;
  float s[14];
  #pragma unroll
  for (int kk=0;kk<14;kk++) s[kk]=0.0f;
  for (int t=tid; t<T_; t+=256){
    float x0 = pb[0*T_+t], x1 = pb[1*T_+t], x2 = pb[2*T_+t], x3 = pb[3*T_+t];
    s[0]+=x0; s[1]+=x1; s[2]+=x2; s[3]+=x3;
    s[4]+=x0*x0; s[5]+=x1*x0; s[6]+=x1*x1; s[7]+=x2*x0; s[8]+=x2*x1;
    s[9]+=x2*x2; s[10]+=x3*x0; s[11]+=x3*x1; s[12]+=x3*x2; s[13]+=x3*x3;
  }
  #pragma unroll
  for (int kk=0;kk<14;kk++){
    #pragma unroll
    for (int off=1; off<64; off<<=1)
      s[kk] += __shfl_xor(s[kk], off, 64);
  }
  if (lane == 0){
    #pragma unroll
    for (int kk=0;kk<14;kk++) red[wave][kk] = s[kk];
  }
  __syncthreads();
  if (tid == 0){
    float tot[14];
    #pragma unroll
    for (int kk=0;kk<14;kk++)
      tot[kk] = red[0][kk] + red[1][kk] + red[2][kk] + red[3][kk];
    const float invT  = 1.0f/(float)T_;
    const float invT1 = 1.0f/(float)(T_-1);
    float csum = 0.0f;
    #pragma unroll
    for (int n=0;n<4;n++){
      #pragma unroll
      for (int m=0;m<=n;m++){
        int id = n*(n+1)/2 + m;
        float c = (tot[4+id] - tot[n]*tot[m]*invT) * invT1;
        csum += (n==m) ? fabsf(c) : 2.0f*fabsf(c);
      }
    }
    partial[b] = 0.5f*csum;
  }
}

__global__ void loss_final_kernel(const float* __restrict__ partial,
                                  float* __restrict__ simOut){
  if (threadIdx.x == 0){
    float sim = 0.0f;
    #pragma unroll
    for (int b=0;b<B_;b++) sim += partial[b];
    simOut[0] = sim * (1.0f/(float)B_);
  }
}

// ----------------------------------------------------------------- launch
extern "C" void kernel_launch(void* const* d_in, const int* in_sizes, int n_in,
                              void* d_out, int out_size, void* d_ws, size_t ws_size,
                              hipStream_t stream)
{
  const float* q  = (const float*)d_in[0];
  const float* k  = (const float*)d_in[1];
  const float* v  = (const float*)d_in[2];
  const float* wq = (const float*)d_in[3];
  const float* bq = (const float*)d_in[4];
  const float* wk = (const float*)d_in[5];
  const float* bk = (const float*)d_in[6];
  const float* wv = (const float*)d_in[7];
  const float* bv = (const float*)d_in[8];
  const float* wp = (const float*)d_in[9];
  const float* bp = (const float*)d_in[10];
  float* out = (float*)d_out;

  // workspace layout (bytes); total ~286.6 MB (same footprint as R2)
  char* ws = (char*)d_ws;
  u16* qbf   = (u16*)(ws + 0);          // 16 MB  (dead after qp GEMM)
  u16* kbf   = (u16*)(ws + 16777216);   // 16 MB  (dead after kp GEMM)
  u16* vbf   = (u16*)(ws + 33554432);   // 16 MB
  u16* wqbf  = (u16*)(ws + 50331648);   // 128 KB
  u16* wkbf  = (u16*)(ws + 50462720);   // 128 KB
  u16* wvbf  = (u16*)(ws + 50593792);   // 512 KB
  u16* qpbf  = (u16*)(ws + 51118080);   // 16 MB  [B*T][R] bf16
  u16* kpbf  = (u16*)(ws + 67895296);   // 16 MB
  u16* vtbf  = (u16*)(ws + 84672512);   // 64 MB  [B][NS*R][T] bf16 (vs^T, +bias)
  u16* pbuf  = (u16*)(ws + 151781376);  // 128 MB [B][T][T] bf16 (p' = exp(v))
  float* prj = (float*)(ws + 285999104);// 512 KB [B][NS][T] f32
  float* lpart = (float*)(ws + 0);      // 64 B, reuses dead qbf region
  float* lsum  = (float*)(ws + 16777216); // 128 KB [B][T] f32, reuses dead kbf

  // 0) fp32 -> bf16 conversions
  cvt_kernel<<<8192,256,0,stream>>>(q,  qbf, 2097152);
  cvt_kernel<<<8192,256,0,stream>>>(k,  kbf, 2097152);
  cvt_kernel<<<8192,256,0,stream>>>(v,  vbf, 2097152);
  cvt_kernel<<<64,  256,0,stream>>>(wq, wqbf, 16384);
  cvt_kernel<<<64,  256,0,stream>>>(wk, wkbf, 16384);
  cvt_kernel<<<256, 256,0,stream>>>(wv, wvbf, 65536);

  // 1) projections: qp = q@wq^T+bq, kp = k@wk^T+bk  (M=32768,N=256,K=256)
  dim3 gq(2,256,1);
  gemm_nt_bias<<<gq,256,0,stream>>>(qbf, wqbf, qpbf, bq, 256,256,256,256, 0,0,0, 0, 0);
  gemm_nt_bias<<<gq,256,0,stream>>>(kbf, wkbf, kpbf, bk, 256,256,256,256, 0,0,0, 0, 0);
  // vs^T: per (b,n): C[o][t] = wv[n] @ v[b]^T + bv[n]  (M=256,N=2048,K=256)
  dim3 gv(16,2,64);
  gemm_nt_bias<<<gv,256,0,stream>>>(wvbf, vbf, vtbf, bv, 256,256,2048,256,
                                    65536LL, 524288LL, 524288LL, 256, 1);

  // 2) zero l table (kbf is dead now), then single-sweep attention
  zero_kernel<<<128,256,0,stream>>>(lsum, 32768);
  dim3 ga(272,16,1);
  attn_kernel<<<ga,256,0,stream>>>(qpbf, kpbf, pbuf, lsum);

  // 3) out = (P' @ Vcat) / l
  dim3 gp(8,16,16);
  pv_kernel<<<gp,256,0,stream>>>(pbuf, vtbf, lsum, out);

  // 4) sim loss (proj -> per-batch cov partials -> final mean)
  proj_kernel<<<512,256,0,stream>>>(vtbf, wp, bp, prj);
  loss_batch_kernel<<<16,256,0,stream>>>(prj, lpart);
  loss_final_kernel<<<1,64,0,stream>>>(lpart, out + 33554432);
}

// Round 4
// 482.321 us; speedup vs baseline: 1.6247x; 1.0864x over previous
//
#include <hip/hip_runtime.h>

#define B_  16
#define T_  2048
#define R_  256
#define NS_ 4

typedef unsigned short u16;
typedef __attribute__((ext_vector_type(8))) __bf16 bf16x8;
typedef __attribute__((ext_vector_type(4))) float f32x4;

__device__ __forceinline__ u16 f2bf(float f){
  union { float f; unsigned u; } x; x.f = f;
  unsigned r = x.u + 0x7FFFu + ((x.u >> 16) & 1u);
  return (u16)(r >> 16);
}
__device__ __forceinline__ float bf2f(u16 h){
  union { unsigned u; float f; } x; x.u = ((unsigned)h) << 16; return x.f;
}

// async global->LDS, 16B per lane. LDS dest must be wave-uniform base; HW
// writes lane i at base + i*16 (guide §5). Our chunk order matches that.
__device__ __forceinline__ void async_cp16(const void* g, void* l){
  __builtin_amdgcn_global_load_lds((__attribute__((address_space(1))) void*)g,
                                   (__attribute__((address_space(3))) void*)l,
                                   16, 0, 0);
}

// ---------------------------------------------------------------- convert
__global__ __launch_bounds__(256)
void cvt_kernel(const float* __restrict__ src, u16* __restrict__ dst, int n4){
  int i = blockIdx.x*256 + threadIdx.x;
  if (i >= n4) return;
  float4 f = ((const float4*)src)[i];
  ushort4 o;
  o.x = f2bf(f.x); o.y = f2bf(f.y); o.z = f2bf(f.z); o.w = f2bf(f.w);
  ((ushort4*)dst)[i] = o;
}

__global__ __launch_bounds__(256)
void zero_kernel(float* __restrict__ p, int n){
  int i = blockIdx.x*256 + threadIdx.x;
  if (i < n) p[i] = 0.0f;
}

// ------------------------------------------------- generic NT GEMM (bf16)
// C[m][n] = sum_k A[m][k]*B[n][k] + bias ; C stored bf16.
// z decode: n = z&3 (weight/bias select), b = z>>2 (batch select).
// biasMode 0: bias indexed by col (N). biasMode 1: bias indexed by row (M).
__global__ __launch_bounds__(256, 2)
void gemm_nt_bias(const u16* __restrict__ A, const u16* __restrict__ Bm,
                  u16* __restrict__ C, const float* __restrict__ bias,
                  int lda, int ldb, int ldc, int K,
                  long long sAn, long long sBb, long long sCz,
                  int sBiasN, int biasMode)
{
  __shared__ __align__(16) u16 As[128*32];
  __shared__ __align__(16) u16 Bs[128*32];
  int tid = threadIdx.x;
  int lane = tid & 63, wave = tid >> 6;
  int z = blockIdx.z;
  int nIdx = z & 3, bIdx = z >> 2;
  A    += (long long)nIdx * sAn;
  Bm   += (long long)bIdx * sBb;
  C    += (long long)z * sCz;
  bias += (long long)nIdx * sBiasN;
  int mBase = blockIdx.y * 128;
  int nBase = blockIdx.x * 128;
  int wm = (wave >> 1) * 64, wn = (wave & 1) * 64;
  int quad = lane >> 4, lc = lane & 15;

  f32x4 acc[4][4];
  #pragma unroll
  for (int i=0;i<4;i++)
    #pragma unroll
    for (int j=0;j<4;j++) acc[i][j] = (f32x4){0.f,0.f,0.f,0.f};

  for (int k0=0; k0<K; k0+=32){
    #pragma unroll
    for (int r=0;r<2;r++){
      int c = r*256 + tid;
      int row = c >> 2, col = (c & 3)*8;
      async_cp16(A  + (long long)(mBase+row)*lda + k0 + col, (void*)(As + (r*256 + wave*64)*8));
      async_cp16(Bm + (long long)(nBase+row)*ldb + k0 + col, (void*)(Bs + (r*256 + wave*64)*8));
    }
    __syncthreads();
    bf16x8 af[4], bfr[4];
    #pragma unroll
    for (int i=0;i<4;i++){
      af[i]  = *(const bf16x8*)(As + (wm + i*16 + lc)*32 + quad*8);
      bfr[i] = *(const bf16x8*)(Bs + (wn + i*16 + lc)*32 + quad*8);
    }
    #pragma unroll
    for (int i=0;i<4;i++)
      #pragma unroll
      for (int j=0;j<4;j++)
        acc[i][j] = __builtin_amdgcn_mfma_f32_16x16x32_bf16(af[i], bfr[j], acc[i][j], 0,0,0);
    __syncthreads();
  }
  // epilogue: C/D layout col=lane&15, row=quad*4+e (m89/m91 verified)
  #pragma unroll
  for (int i=0;i<4;i++){
    #pragma unroll
    for (int j=0;j<4;j++){
      int colG = nBase + wn + j*16 + lc;
      float bc = (biasMode==0) ? bias[colG] : 0.0f;
      #pragma unroll
      for (int e=0;e<4;e++){
        int rowG = mBase + wm + i*16 + quad*4 + e;
        float val = acc[i][j][e] + ((biasMode==0) ? bc : bias[rowG]);
        C[(long long)rowG*ldc + colG] = f2bf(val);
      }
    }
  }
}

// ------------------------------------- attention scores, single sweep
// One block per (b, 64-row t-tile, 128-col s-tile). No max subtraction:
// scores here are bounded (|v| ~< 10 << 88), so p' = exp(v) is overflow-safe
// and softmax = p'/sum(p') exactly. Masked (s>t or v==0) -> exp(-10000) = 0
// in fp32, matching the reference tril+where quirk. Row sums accumulate via
// fp32 atomicAdd into l[B][T]; pv_kernel divides by l in its epilogue.
__global__ __launch_bounds__(256, 4)
void attn_kernel(const u16* __restrict__ qp, const u16* __restrict__ kp,
                 u16* __restrict__ P, float* __restrict__ lsum)
{
  __shared__ __align__(16) u16 Qs[64*32];
  __shared__ __align__(16) u16 Ks[128*32];
  int tid = threadIdx.x, lane = tid & 63, wave = tid >> 6;
  int b = blockIdx.y;
  // heavy-first flat decode: t64 descending, c(t64)=t64/2+1 s-tiles
  int f = blockIdx.x;
  int t64 = 31;
  while (f >= (t64 >> 1) + 1){ f -= (t64 >> 1) + 1; t64--; }
  int sT = f;
  int tBase = t64 * 64;
  const u16* Q  = qp + ((long long)b*T_ + tBase) * R_;
  const u16* Kt = kp + (long long)b*T_*R_ + (long long)sT*128*R_;
  u16* Pb = P + (long long)b*T_*T_;
  const float scale = 0.0625f;     // 1/sqrt(256)
  int quad = lane >> 4, lc = lane & 15;
  int rowLoc = wave*16 + quad*4;

  f32x4 acc[8];
  #pragma unroll
  for (int j=0;j<8;j++) acc[j] = (f32x4){0.f,0.f,0.f,0.f};

  for (int k0=0;k0<R_;k0+=32){
    {
      int row = tid >> 2, col = (tid & 3)*8;
      async_cp16(Q + (long long)row*R_ + k0 + col, (void*)(Qs + (wave*64)*8));
    }
    #pragma unroll
    for (int r=0;r<2;r++){
      int c = r*256 + tid;
      int row = c >> 2, col = (c & 3)*8;
      async_cp16(Kt + (long long)row*R_ + k0 + col, (void*)(Ks + (r*256 + wave*64)*8));
    }
    __syncthreads();
    bf16x8 aq = *(const bf16x8*)(Qs + (wave*16 + lc)*32 + quad*8);
    #pragma unroll
    for (int j=0;j<8;j++){
      bf16x8 bk = *(const bf16x8*)(Ks + (j*16 + lc)*32 + quad*8);
      acc[j] = __builtin_amdgcn_mfma_f32_16x16x32_bf16(aq, bk, acc[j], 0,0,0);
    }
    __syncthreads();
  }

  int sCol0 = sT*128 + lc;
  #pragma unroll
  for (int e=0;e<4;e++){
    int t = tBase + rowLoc + e;
    long long ro = (long long)t * T_;
    float rs = 0.0f;
    #pragma unroll
    for (int j=0;j<8;j++){
      float v = acc[j][e]*scale;
      int s = sCol0 + j*16;
      if (s > t || v == 0.0f) v = -10000.0f;
      float p = __expf(v);            // exact 0 when masked
      rs += p;
      Pb[ro + s] = f2bf(p);
    }
    // sum across the 16 lc-lanes of this quad (they hold cols of row t)
    #pragma unroll
    for (int off=1; off<16; off<<=1)
      rs += __shfl_xor(rs, off, 64);
    if (lc == 0)
      atomicAdd(&lsum[b*T_ + t], rs);
  }
}

// --------------------------------------------------------------- PV GEMM
// out[b][n][t][r] = (1/l[t]) * sum_s P'[b][t][s] * VT[b][n*256+r][s]
// K limited to t0+128 (P' diagonal tile holds exact zeros above the
// diagonal; tiles beyond are never written and never read).
// R4: 1D swizzled grid — the 8 j-blocks sharing one P-tile are placed with
// identical (blockIdx%8) so they land on the same XCD (round-robin
// heuristic) and adjacent dispatch slots: P tile fetched once per L2.
// tTiles interleave across XCDs heavy-first (t0 descending with dispatch).
__global__ __launch_bounds__(256, 4)
void pv_kernel(const u16* __restrict__ P, const u16* __restrict__ VT,
               const float* __restrict__ lsum, float* __restrict__ out)
{
  __shared__ __align__(16) u16 As[128*32];
  __shared__ __align__(16) u16 Bs[128*32];
  int tid = threadIdx.x, lane = tid & 63, wave = tid >> 6;
  int f = blockIdx.x;              // 0..2047
  int kf = f >> 3;
  int gr = (f & 7) + 8*(kf >> 3);  // group 0..255, gr%8 = XCD slot
  int jIdx  = kf & 7;              // 8 j-blocks of a group: adjacent kf
  int b     = gr & 15;
  int tTile = 15 - (gr >> 4);      // heavy-first
  int jBase = jIdx * 128;
  int t0 = tTile * 128;
  int K = t0 + 128;
  const u16* A  = P  + (long long)b*T_*T_ + (long long)t0*T_;
  const u16* Bm = VT + (long long)b*1024*T_ + (long long)jBase*T_;
  const float* lrow = lsum + b*T_;
  int wm = (wave>>1)*64, wn = (wave&1)*64;
  int quad = lane>>4, lc = lane&15;

  f32x4 acc[4][4];
  #pragma unroll
  for (int i=0;i<4;i++)
    #pragma unroll
    for (int j=0;j<4;j++) acc[i][j] = (f32x4){0.f,0.f,0.f,0.f};

  for (int k0=0; k0<K; k0+=32){
    #pragma unroll
    for (int r=0;r<2;r++){
      int c = r*256 + tid;
      int row = c >> 2, col = (c & 3)*8;
      async_cp16(A  + (long long)row*T_ + k0 + col, (void*)(As + (r*256 + wave*64)*8));
      async_cp16(Bm + (long long)row*T_ + k0 + col, (void*)(Bs + (r*256 + wave*64)*8));
    }
    __syncthreads();
    bf16x8 af[4], bfr[4];
    #pragma unroll
    for (int i=0;i<4;i++){
      af[i]  = *(const bf16x8*)(As + (wm + i*16 + lc)*32 + quad*8);
      bfr[i] = *(const bf16x8*)(Bs + (wn + i*16 + lc)*32 + quad*8);
    }
    #pragma unroll
    for (int i=0;i<4;i++)
      #pragma unroll
      for (int j=0;j<4;j++)
        acc[i][j] = __builtin_amdgcn_mfma_f32_16x16x32_bf16(af[i], bfr[j], acc[i][j], 0,0,0);
    __syncthreads();
  }
  #pragma unroll
  for (int i=0;i<4;i++){
    float rl[4];
    #pragma unroll
    for (int e=0;e<4;e++)
      rl[e] = __builtin_amdgcn_rcpf(lrow[t0 + wm + i*16 + quad*4 + e]);
    #pragma unroll
    for (int j=0;j<4;j++){
      int colJ = jBase + wn + j*16 + lc;
      int n = colJ >> 8, r = colJ & 255;
      #pragma unroll
      for (int e=0;e<4;e++){
        int t = t0 + wm + i*16 + quad*4 + e;
        out[(((long long)b*NS_ + n)*T_ + t)*R_ + r] = acc[i][j][e] * rl[e];
      }
    }
  }
}

// ------------------------------------------------------------------ proj
// proj[b][n][t] = sum_o VT[b][n*256+o][t] * wp[o] + bp  (coalesced over t)
__global__ __launch_bounds__(256)
void proj_kernel(const u16* __restrict__ VT, const float* __restrict__ wp,
                 const float* __restrict__ bp, float* __restrict__ proj){
  int gid = blockIdx.x*256 + threadIdx.x;   // 16*4*2048
  int bn = gid >> 11, t = gid & 2047;
  const u16* base = VT + (long long)bn*R_*T_ + t;
  float acc = bp[0];
  #pragma unroll 8
  for (int o=0;o<R_;o++)
    acc = fmaf(bf2f(base[(long long)o*T_]), wp[o], acc);
  proj[gid] = acc;
}

// ------------------------------------------------------- cov + loss
__global__ __launch_bounds__(256)
void loss_batch_kernel(const float* __restrict__ proj, float* __restrict__ partial){
  __shared__ float red[4][14];
  int tid = threadIdx.x, lane = tid & 63, wave = tid >> 6;
  int b = blockIdx.x;
  const float* pb = proj + b*NS_*T_;
  float s[14];
  #pragma unroll
  for (int kk=0;kk<14;kk++) s[kk]=0.0f;
  for (int t=tid; t<T_; t+=256){
    float x0 = pb[0*T_+t], x1 = pb[1*T_+t], x2 = pb[2*T_+t], x3 = pb[3*T_+t];
    s[0]+=x0; s[1]+=x1; s[2]+=x2; s[3]+=x3;
    s[4]+=x0*x0; s[5]+=x1*x0; s[6]+=x1*x1; s[7]+=x2*x0; s[8]+=x2*x1;
    s[9]+=x2*x2; s[10]+=x3*x0; s[11]+=x3*x1; s[12]+=x3*x2; s[13]+=x3*x3;
  }
  #pragma unroll
  for (int kk=0;kk<14;kk++){
    #pragma unroll
    for (int off=1; off<64; off<<=1)
      s[kk] += __shfl_xor(s[kk], off, 64);
  }
  if (lane == 0){
    #pragma unroll
    for (int kk=0;kk<14;kk++) red[wave][kk] = s[kk];
  }
  __syncthreads();
  if (tid == 0){
    float tot[14];
    #pragma unroll
    for (int kk=0;kk<14;kk++)
      tot[kk] = red[0][kk] + red[1][kk] + red[2][kk] + red[3][kk];
    const float invT  = 1.0f/(float)T_;
    const float invT1 = 1.0f/(float)(T_-1);
    float csum = 0.0f;
    #pragma unroll
    for (int n=0;n<4;n++){
      #pragma unroll
      for (int m=0;m<=n;m++){
        int id = n*(n+1)/2 + m;
        float c = (tot[4+id] - tot[n]*tot[m]*invT) * invT1;
        csum += (n==m) ? fabsf(c) : 2.0f*fabsf(c);
      }
    }
    partial[b] = 0.5f*csum;
  }
}

__global__ void loss_final_kernel(const float* __restrict__ partial,
                                  float* __restrict__ simOut){
  if (threadIdx.x == 0){
    float sim = 0.0f;
    #pragma unroll
    for (int b=0;b<B_;b++) sim += partial[b];
    simOut[0] = sim * (1.0f/(float)B_);
  }
}

// ----------------------------------------------------------------- launch
extern "C" void kernel_launch(void* const* d_in, const int* in_sizes, int n_in,
                              void* d_out, int out_size, void* d_ws, size_t ws_size,
                              hipStream_t stream)
{
  const float* q  = (const float*)d_in[0];
  const float* k  = (const float*)d_in[1];
  const float* v  = (const float*)d_in[2];
  const float* wq = (const float*)d_in[3];
  const float* bq = (const float*)d_in[4];
  const float* wk = (const float*)d_in[5];
  const float* bk = (const float*)d_in[6];
  const float* wv = (const float*)d_in[7];
  const float* bv = (const float*)d_in[8];
  const float* wp = (const float*)d_in[9];
  const float* bp = (const float*)d_in[10];
  float* out = (float*)d_out;

  // workspace layout (bytes); total ~286.6 MB
  char* ws = (char*)d_ws;
  u16* qbf   = (u16*)(ws + 0);          // 16 MB  (dead after qp GEMM)
  u16* kbf   = (u16*)(ws + 16777216);   // 16 MB  (dead after kp GEMM)
  u16* vbf   = (u16*)(ws + 33554432);   // 16 MB
  u16* wqbf  = (u16*)(ws + 50331648);   // 128 KB
  u16* wkbf  = (u16*)(ws + 50462720);   // 128 KB
  u16* wvbf  = (u16*)(ws + 50593792);   // 512 KB
  u16* qpbf  = (u16*)(ws + 51118080);   // 16 MB  [B*T][R] bf16
  u16* kpbf  = (u16*)(ws + 67895296);   // 16 MB
  u16* vtbf  = (u16*)(ws + 84672512);   // 64 MB  [B][NS*R][T] bf16 (vs^T, +bias)
  u16* pbuf  = (u16*)(ws + 151781376);  // 128 MB [B][T][T] bf16 (p' = exp(v))
  float* prj = (float*)(ws + 285999104);// 512 KB [B][NS][T] f32
  float* lpart = (float*)(ws + 0);      // 64 B, reuses dead qbf region
  float* lsum  = (float*)(ws + 16777216); // 128 KB [B][T] f32, reuses dead kbf

  // 0) fp32 -> bf16 conversions
  cvt_kernel<<<8192,256,0,stream>>>(q,  qbf, 2097152);
  cvt_kernel<<<8192,256,0,stream>>>(k,  kbf, 2097152);
  cvt_kernel<<<8192,256,0,stream>>>(v,  vbf, 2097152);
  cvt_kernel<<<64,  256,0,stream>>>(wq, wqbf, 16384);
  cvt_kernel<<<64,  256,0,stream>>>(wk, wkbf, 16384);
  cvt_kernel<<<256, 256,0,stream>>>(wv, wvbf, 65536);

  // 1) projections: qp = q@wq^T+bq, kp = k@wk^T+bk  (M=32768,N=256,K=256)
  dim3 gq(2,256,1);
  gemm_nt_bias<<<gq,256,0,stream>>>(qbf, wqbf, qpbf, bq, 256,256,256,256, 0,0,0, 0, 0);
  gemm_nt_bias<<<gq,256,0,stream>>>(kbf, wkbf, kpbf, bk, 256,256,256,256, 0,0,0, 0, 0);
  // vs^T: per (b,n): C[o][t] = wv[n] @ v[b]^T + bv[n]  (M=256,N=2048,K=256)
  dim3 gv(16,2,64);
  gemm_nt_bias<<<gv,256,0,stream>>>(wvbf, vbf, vtbf, bv, 256,256,2048,256,
                                    65536LL, 524288LL, 524288LL, 256, 1);

  // 2) zero l table (kbf is dead now), then single-sweep attention
  zero_kernel<<<128,256,0,stream>>>(lsum, 32768);
  dim3 ga(272,16,1);
  attn_kernel<<<ga,256,0,stream>>>(qpbf, kpbf, pbuf, lsum);

  // 3) out = (P' @ Vcat) / l   (XCD-swizzled 1D grid)
  pv_kernel<<<2048,256,0,stream>>>(pbuf, vtbf, lsum, out);

  // 4) sim loss (proj -> per-batch cov partials -> final mean)
  proj_kernel<<<512,256,0,stream>>>(vtbf, wp, bp, prj);
  loss_batch_kernel<<<16,256,0,stream>>>(prj, lpart);
  loss_final_kernel<<<1,64,0,stream>>>(lpart, out + 33554432);
}